// Round 1
// baseline (129.287 us; speedup 1.0000x reference)
//
#include <hip/hip_runtime.h>
#include <hip/hip_bf16.h>

#define H 2048
#define BN 64
#define TT 4096
#define BB 4
#define KK 128

// ---------------------------------------------------------------------------
// Kernel A: logits[row] = dot(x[row,:], Wg) + bg  — one wave64 per row
// ---------------------------------------------------------------------------
__global__ __launch_bounds__(256) void logits_kernel(
    const float* __restrict__ x, const float* __restrict__ Wg,
    const float* __restrict__ bg, float* __restrict__ logits, int nrows) {
    int gtid = blockIdx.x * blockDim.x + threadIdx.x;
    int row  = gtid >> 6;
    int lane = threadIdx.x & 63;
    if (row >= nrows) return;
    const float4* x4 = (const float4*)(x + (size_t)row * H);
    const float4* w4 = (const float4*)Wg;
    float acc = 0.f;
#pragma unroll
    for (int i = 0; i < 8; ++i) {  // 64 lanes * 8 float4 = 512 float4 = 2048 floats
        float4 a = x4[lane + 64 * i];
        float4 b = w4[lane + 64 * i];
        acc += a.x * b.x + a.y * b.y + a.z * b.z + a.w * b.w;
    }
#pragma unroll
    for (int off = 32; off > 0; off >>= 1) acc += __shfl_down(acc, off);
    if (lane == 0) logits[row] = acc + bg[0];
}

// ---------------------------------------------------------------------------
// Kernel B: per batch row, top-K mask via 32-bit MSB radix-select in LDS.
// Ties at the threshold value are taken in ascending index order (lax.top_k).
// ---------------------------------------------------------------------------
__global__ __launch_bounds__(256) void topk_mask_kernel(
    const float* __restrict__ logits, unsigned* __restrict__ mask) {
    __shared__ unsigned keys[TT];
    __shared__ int red[256];
    __shared__ int eqoff[256];
    const int tid = threadIdx.x;
    const int b   = blockIdx.x;
    const float* lr = logits + (size_t)b * TT;
    unsigned* mr    = mask + (size_t)b * TT;

    // monotone float->uint key
    for (int i = tid; i < TT; i += 256) {
        unsigned u = __float_as_uint(lr[i]);
        keys[i] = (u & 0x80000000u) ? ~u : (u | 0x80000000u);
    }
    __syncthreads();

    // radix select: value of the k-th largest key
    unsigned prefix = 0;
    int k = KK;
    for (int bit = 31; bit >= 0; --bit) {
        unsigned test = prefix | (1u << bit);
        unsigned ref  = test >> bit;
        int cnt = 0;
        for (int i = tid; i < TT; i += 256)
            if ((keys[i] >> bit) == ref) cnt++;
        red[tid] = cnt;
        __syncthreads();
        for (int s = 128; s > 0; s >>= 1) {
            if (tid < s) red[tid] += red[tid + s];
            __syncthreads();
        }
        int total = red[0];
        __syncthreads();
        if (total >= k) prefix = test;
        else            k -= total;
    }

    // count strictly-greater, and index-ordered rank among equals
    const int per = TT / 256;        // 16, contiguous chunk per thread
    const int i0 = tid * per, i1 = i0 + per;
    int cgt = 0, ceq = 0;
    for (int i = i0; i < i1; ++i) {
        if (keys[i] > prefix) cgt++;
        else if (keys[i] == prefix) ceq++;
    }
    red[tid] = cgt;
    __syncthreads();
    for (int s = 128; s > 0; s >>= 1) {
        if (tid < s) red[tid] += red[tid + s];
        __syncthreads();
    }
    int total_gt = red[0];
    __syncthreads();
    red[tid] = ceq;
    __syncthreads();
    if (tid == 0) {
        int s = 0;
        for (int i = 0; i < 256; ++i) { eqoff[i] = s; s += red[i]; }
    }
    __syncthreads();

    int need_eq = KK - total_gt;
    int rank = eqoff[tid];
    for (int i = i0; i < i1; ++i) {
        unsigned m = 0;
        if (keys[i] > prefix) m = 1;
        else if (keys[i] == prefix) { if (rank < need_eq) m = 1; rank++; }
        mr[i] = m;
    }
}

// ---------------------------------------------------------------------------
// Kernel C: one block per row. Unmasked: out=x (pure copy). Masked:
// out = x + relu(x@Wd + bd)@Wu + bu, fused in-block.
// ---------------------------------------------------------------------------
__global__ __launch_bounds__(256) void out_kernel(
    const float* __restrict__ x, const float* __restrict__ Wd,
    const float* __restrict__ bd, const float* __restrict__ Wu,
    const float* __restrict__ bu, const unsigned* __restrict__ mask,
    float* __restrict__ out) {
    const int row = blockIdx.x;
    const int tid = threadIdx.x;
    const float* xr = x + (size_t)row * H;
    float* orow     = out + (size_t)row * H;
    const float4* x4 = (const float4*)xr;
    float4* o4       = (float4*)orow;

    if (!mask[row]) {                 // uniform per-block branch
        o4[tid]       = x4[tid];
        o4[tid + 256] = x4[tid + 256];
        return;
    }

    __shared__ float xs[H];
    __shared__ float hp[4][BN];
    __shared__ float hs[BN];

    float4 a0 = x4[tid];
    float4 a1 = x4[tid + 256];
    ((float4*)xs)[tid]       = a0;
    ((float4*)xs)[tid + 256] = a1;
    __syncthreads();

    // h_j = relu(sum_h xs[h]*Wd[h][j] + bd[j]); 4 groups x 64 j-lanes
    const int j = tid & 63, g = tid >> 6;
    {
        float acc = 0.f;
        const float* wd = Wd + (size_t)(g * (H / 4)) * BN + j;
        const float* xg = xs + g * (H / 4);
        for (int h = 0; h < H / 4; ++h) acc += xg[h] * wd[(size_t)h * BN];
        hp[g][j] = acc;
    }
    __syncthreads();
    if (tid < BN) {
        float v = hp[0][tid] + hp[1][tid] + hp[2][tid] + hp[3][tid] + bd[tid];
        hs[tid] = v > 0.f ? v : 0.f;
    }
    __syncthreads();

    // y_o = sum_j hs[j]*Wu[j][o] + bu[o]; each thread owns 8 outputs
    float y[8];
#pragma unroll
    for (int r = 0; r < 8; ++r) y[r] = bu[tid + 256 * r];
    for (int jj = 0; jj < BN; ++jj) {
        float hv = hs[jj];
        const float* wu = Wu + (size_t)jj * H;
#pragma unroll
        for (int r = 0; r < 8; ++r) y[r] += hv * wu[tid + 256 * r];
    }
#pragma unroll
    for (int r = 0; r < 8; ++r) orow[tid + 256 * r] = xr[tid + 256 * r] + y[r];
}

// ---------------------------------------------------------------------------
extern "C" void kernel_launch(void* const* d_in, const int* in_sizes, int n_in,
                              void* d_out, int out_size, void* d_ws, size_t ws_size,
                              hipStream_t stream) {
    const float* x  = (const float*)d_in[0];
    const float* Wd = (const float*)d_in[1];
    const float* bd = (const float*)d_in[2];
    const float* Wu = (const float*)d_in[3];
    const float* bu = (const float*)d_in[4];
    const float* Wg = (const float*)d_in[5];
    const float* bg = (const float*)d_in[6];
    float* out = (float*)d_out;

    const int nrows = in_sizes[0] / H;           // 16384 = B*T
    float*    logits = (float*)d_ws;             // nrows floats
    unsigned* mask   = (unsigned*)((char*)d_ws + (size_t)nrows * sizeof(float));

    // A: logits (one wave per row, 4 waves/block)
    logits_kernel<<<(nrows + 3) / 4, 256, 0, stream>>>(x, Wg, bg, logits, nrows);
    // B: per-batch top-K mask
    topk_mask_kernel<<<BB, 256, 0, stream>>>(logits, mask);
    // C: output
    out_kernel<<<nrows, 256, 0, stream>>>(x, Wd, bd, Wu, bu, mask, out);
}

// Round 2
// 114.624 us; speedup vs baseline: 1.1279x; 1.1279x over previous
//
#include <hip/hip_runtime.h>
#include <hip/hip_bf16.h>

#define H 2048
#define BN 64
#define TT 4096
#define BB 4
#define KK 128

// ---------------------------------------------------------------------------
// Kernel 1: fused  out = x  (full copy)  +  logits = x @ Wg + bg.
// One wave64 per row; x is read from HBM exactly once.
// ---------------------------------------------------------------------------
__global__ __launch_bounds__(256) void copy_logits_kernel(
    const float* __restrict__ x, const float* __restrict__ Wg,
    const float* __restrict__ bg, float* __restrict__ out,
    float* __restrict__ logits, int nrows) {
    int row  = (blockIdx.x * blockDim.x + threadIdx.x) >> 6;
    int lane = threadIdx.x & 63;
    if (row >= nrows) return;
    const float4* x4 = (const float4*)(x + (size_t)row * H);
    float4*       o4 = (float4*)(out + (size_t)row * H);
    const float4* w4 = (const float4*)Wg;
    float acc = 0.f;
#pragma unroll
    for (int i = 0; i < 8; ++i) {   // 64 lanes * 8 * float4 = 2048 floats
        float4 a = x4[lane + 64 * i];
        float4 b = w4[lane + 64 * i];   // 8KB, L1-resident across rows
        o4[lane + 64 * i] = a;
        acc += a.x * b.x + a.y * b.y + a.z * b.z + a.w * b.w;
    }
#pragma unroll
    for (int off = 32; off > 0; off >>= 1) acc += __shfl_down(acc, off);
    if (lane == 0) logits[row] = acc + bg[0];
}

// ---------------------------------------------------------------------------
// Kernel 2: per batch, top-K selection -> compact index list (global row ids).
// 32-bit MSB radix select; ties taken in ascending index order (lax.top_k).
// Wave-level reductions (no LDS tree in the bit loop).
// ---------------------------------------------------------------------------
__global__ __launch_bounds__(256) void topk_idx_kernel(
    const float* __restrict__ logits, int* __restrict__ idxlist) {
    __shared__ unsigned keys[TT];
    __shared__ int wsum[4];
    __shared__ int gtp[256], eqp[256];
    const int tid = threadIdx.x;
    const int b   = blockIdx.x;
    const float* lr = logits + (size_t)b * TT;

    // monotone float -> uint key
    for (int i = tid; i < TT; i += 256) {
        unsigned u = __float_as_uint(lr[i]);
        keys[i] = (u & 0x80000000u) ? ~u : (u | 0x80000000u);
    }
    __syncthreads();

    // radix select the K-th largest key value
    unsigned prefix = 0;
    int k = KK;
    for (int bit = 31; bit >= 0; --bit) {
        unsigned ref = (prefix >> bit) | 1u;
        int c = 0;
        for (int i = tid; i < TT; i += 256) c += ((keys[i] >> bit) == ref);
#pragma unroll
        for (int off = 32; off > 0; off >>= 1) c += __shfl_down(c, off);
        if ((tid & 63) == 0) wsum[tid >> 6] = c;
        __syncthreads();
        int total = wsum[0] + wsum[1] + wsum[2] + wsum[3];
        __syncthreads();                       // wsum reused next iteration
        if (total >= k) prefix |= (1u << bit);
        else            k -= total;
    }

    // per-thread contiguous chunk: count >prefix and ==prefix
    const int per = TT / 256, i0 = tid * per, i1 = i0 + per;
    int cgt = 0, ceq = 0;
    for (int i = i0; i < i1; ++i) {
        cgt += (keys[i] > prefix);
        ceq += (keys[i] == prefix);
    }
    gtp[tid] = cgt; eqp[tid] = ceq;
    __syncthreads();
    if (tid == 0) {                            // exclusive prefix sums
        int sg = 0, se = 0;
        for (int t = 0; t < 256; ++t) {
            int a = gtp[t]; gtp[t] = sg; sg += a;
            int c = eqp[t]; eqp[t] = se; se += c;
        }
        wsum[0] = sg;                          // total strictly-greater
    }
    __syncthreads();
    const int total_gt = wsum[0];
    const int need_eq  = KK - total_gt;
    int g = gtp[tid], e = eqp[tid];
    int* dst = idxlist + b * KK;
    for (int i = i0; i < i1; ++i) {
        if (keys[i] > prefix)       dst[g++] = b * TT + i;
        else if (keys[i] == prefix) { if (e < need_eq) dst[total_gt + e] = b * TT + i; e++; }
    }
}

// ---------------------------------------------------------------------------
// Kernel 3: adapter rewrite for the BB*KK selected rows only.
// out[row] = x[row] + relu(x[row] @ Wd + bd) @ Wu + bu
// x rows are L3-hot (x fits in 256MiB Infinity Cache); Wd/Wu from L2.
// ---------------------------------------------------------------------------
__global__ __launch_bounds__(256) void adapter_kernel(
    const float* __restrict__ x, const float* __restrict__ Wd,
    const float* __restrict__ bd, const float* __restrict__ Wu,
    const float* __restrict__ bu, const int* __restrict__ idxlist,
    float* __restrict__ out) {
    const int row = idxlist[blockIdx.x];
    const int tid = threadIdx.x;
    const float* xr = x + (size_t)row * H;
    float* orow     = out + (size_t)row * H;

    __shared__ float xs[H];
    __shared__ float hp[4][BN];
    __shared__ float hs[BN];

    ((float4*)xs)[tid]       = ((const float4*)xr)[tid];
    ((float4*)xs)[tid + 256] = ((const float4*)xr)[tid + 256];
    __syncthreads();

    // h_j = relu(sum_h xs[h]*Wd[h][j] + bd[j]); 4 h-groups x 64 j-lanes
    const int j = tid & 63, g = tid >> 6;
    {
        float acc = 0.f;
        const float* wd = Wd + (size_t)(g * (H / 4)) * BN + j;
        const float* xg = xs + g * (H / 4);
#pragma unroll 8
        for (int h = 0; h < H / 4; ++h) acc += xg[h] * wd[(size_t)h * BN];
        hp[g][j] = acc;
    }
    __syncthreads();
    if (tid < BN) {
        float v = hp[0][tid] + hp[1][tid] + hp[2][tid] + hp[3][tid] + bd[tid];
        hs[tid] = v > 0.f ? v : 0.f;
    }
    __syncthreads();

    // y_o = sum_j hs[j]*Wu[j][o] + bu[o]; each thread owns 8 outputs
    float y[8];
#pragma unroll
    for (int r = 0; r < 8; ++r) y[r] = bu[tid + 256 * r];
    for (int jj = 0; jj < BN; ++jj) {
        float hv = hs[jj];
        const float* wu = Wu + (size_t)jj * H;
#pragma unroll
        for (int r = 0; r < 8; ++r) y[r] += hv * wu[tid + 256 * r];
    }
#pragma unroll
    for (int r = 0; r < 8; ++r) orow[tid + 256 * r] = xs[tid + 256 * r] + y[r];
}

// ---------------------------------------------------------------------------
extern "C" void kernel_launch(void* const* d_in, const int* in_sizes, int n_in,
                              void* d_out, int out_size, void* d_ws, size_t ws_size,
                              hipStream_t stream) {
    const float* x  = (const float*)d_in[0];
    const float* Wd = (const float*)d_in[1];
    const float* bd = (const float*)d_in[2];
    const float* Wu = (const float*)d_in[3];
    const float* bu = (const float*)d_in[4];
    const float* Wg = (const float*)d_in[5];
    const float* bg = (const float*)d_in[6];
    float* out = (float*)d_out;

    const int nrows = in_sizes[0] / H;                 // B*T = 16384
    float* logits = (float*)d_ws;                      // nrows floats
    int*   idxlist = (int*)((char*)d_ws + (size_t)nrows * sizeof(float)); // BB*KK ints

    copy_logits_kernel<<<(nrows + 3) / 4, 256, 0, stream>>>(x, Wg, bg, out, logits, nrows);
    topk_idx_kernel<<<BB, 256, 0, stream>>>(logits, idxlist);
    adapter_kernel<<<BB * KK, 256, 0, stream>>>(x, Wd, bd, Wu, bu, idxlist, out);
}

// Round 3
// 102.224 us; speedup vs baseline: 1.2647x; 1.1213x over previous
//
#include <hip/hip_runtime.h>
#include <hip/hip_bf16.h>

#define H 2048
#define BN 64
#define TT 4096
#define BB 4
#define KK 128
#define CP_BLOCKS 1024
#define RPB 4

// ---------------------------------------------------------------------------
// Kernel 1: fused  out = x  +  logits = x @ Wg  (bg dropped: rank-invariant).
// Persistent grid: 1024 blocks = 4/CU resident, 4 rows per wave, Wg in regs.
// ---------------------------------------------------------------------------
__global__ __launch_bounds__(256) void copy_logits_kernel(
    const float* __restrict__ x, const float* __restrict__ Wg,
    float* __restrict__ out, float* __restrict__ logits, int nrows) {
    const int lane   = threadIdx.x & 63;
    const int wave   = (blockIdx.x * 256 + threadIdx.x) >> 6;
    const int nwaves = CP_BLOCKS * 4;
    const float4* w4 = (const float4*)Wg;
    float4 w[8];
#pragma unroll
    for (int i = 0; i < 8; ++i) w[i] = w4[lane + 64 * i];

    for (int row = wave; row < nrows; row += nwaves) {
        const float4* x4 = (const float4*)(x + (size_t)row * H);
        float4*       o4 = (float4*)(out + (size_t)row * H);
        float4 a[8];
#pragma unroll
        for (int i = 0; i < 8; ++i) a[i] = x4[lane + 64 * i];   // 8 loads in flight
        float s0 = 0.f, s1 = 0.f, s2 = 0.f, s3 = 0.f;
#pragma unroll
        for (int i = 0; i < 8; ++i) {
            o4[lane + 64 * i] = a[i];
            s0 = fmaf(a[i].x, w[i].x, s0);
            s1 = fmaf(a[i].y, w[i].y, s1);
            s2 = fmaf(a[i].z, w[i].z, s2);
            s3 = fmaf(a[i].w, w[i].w, s3);
        }
        float acc = (s0 + s1) + (s2 + s3);
#pragma unroll
        for (int off = 32; off > 0; off >>= 1) acc += __shfl_down(acc, off);
        if (lane == 0) logits[row] = acc;
    }
}

// ---------------------------------------------------------------------------
// Kernel 2: per batch, top-K -> compact index list (unchanged, known-correct).
// ---------------------------------------------------------------------------
__global__ __launch_bounds__(256) void topk_idx_kernel(
    const float* __restrict__ logits, int* __restrict__ idxlist) {
    __shared__ unsigned keys[TT];
    __shared__ int wsum[4];
    __shared__ int gtp[256], eqp[256];
    const int tid = threadIdx.x;
    const int b   = blockIdx.x;
    const float* lr = logits + (size_t)b * TT;

    for (int i = tid; i < TT; i += 256) {
        unsigned u = __float_as_uint(lr[i]);
        keys[i] = (u & 0x80000000u) ? ~u : (u | 0x80000000u);
    }
    __syncthreads();

    unsigned prefix = 0;
    int k = KK;
    for (int bit = 31; bit >= 0; --bit) {
        unsigned ref = (prefix >> bit) | 1u;
        int c = 0;
        for (int i = tid; i < TT; i += 256) c += ((keys[i] >> bit) == ref);
#pragma unroll
        for (int off = 32; off > 0; off >>= 1) c += __shfl_down(c, off);
        if ((tid & 63) == 0) wsum[tid >> 6] = c;
        __syncthreads();
        int total = wsum[0] + wsum[1] + wsum[2] + wsum[3];
        __syncthreads();
        if (total >= k) prefix |= (1u << bit);
        else            k -= total;
    }

    const int per = TT / 256, i0 = tid * per, i1 = i0 + per;
    int cgt = 0, ceq = 0;
    for (int i = i0; i < i1; ++i) {
        cgt += (keys[i] > prefix);
        ceq += (keys[i] == prefix);
    }
    gtp[tid] = cgt; eqp[tid] = ceq;
    __syncthreads();
    if (tid == 0) {
        int sg = 0, se = 0;
        for (int t = 0; t < 256; ++t) {
            int a = gtp[t]; gtp[t] = sg; sg += a;
            int c = eqp[t]; eqp[t] = se; se += c;
        }
        wsum[0] = sg;
    }
    __syncthreads();
    const int total_gt = wsum[0];
    const int need_eq  = KK - total_gt;
    int g = gtp[tid], e = eqp[tid];
    int* dst = idxlist + b * KK;
    for (int i = i0; i < i1; ++i) {
        if (keys[i] > prefix)       dst[g++] = b * TT + i;
        else if (keys[i] == prefix) { if (e < need_eq) dst[total_gt + e] = b * TT + i; e++; }
    }
}

// ---------------------------------------------------------------------------
// Kernel 3: adapter, RPB=4 rows per block (128 blocks x 512 threads).
// Down-proj: 8 waves split h (256 each); j = lane; x broadcast via v_readlane
// from registers (VALU pipe, no LDS-broadcast storm). Up-proj: one float4
// output column per thread. Weights read exactly once per block.
// ---------------------------------------------------------------------------
__global__ __launch_bounds__(512) void adapter_kernel(
    const float* __restrict__ x, const float* __restrict__ Wd,
    const float* __restrict__ bd, const float* __restrict__ Wu,
    const float* __restrict__ bu, const int* __restrict__ idxlist,
    float* __restrict__ out) {
    __shared__ float hp[8][RPB][BN];
    __shared__ float hs[RPB][BN];
    const int tid  = threadIdx.x;
    const int lane = tid & 63;       // j-column for down-proj
    const int g    = tid >> 6;       // 0..7 h-group (256 h each)

    int rows[RPB];
#pragma unroll
    for (int r = 0; r < RPB; ++r) rows[r] = idxlist[blockIdx.x * RPB + r];

    // stage x h-chunks into registers: lane holds h = g*256 + k*64 + lane
    float xr0[4], xr1[4], xr2[4], xr3[4];
    {
        const float* p0 = x + (size_t)rows[0] * H + g * 256 + lane;
        const float* p1 = x + (size_t)rows[1] * H + g * 256 + lane;
        const float* p2 = x + (size_t)rows[2] * H + g * 256 + lane;
        const float* p3 = x + (size_t)rows[3] * H + g * 256 + lane;
#pragma unroll
        for (int k = 0; k < 4; ++k) {
            xr0[k] = p0[k * 64]; xr1[k] = p1[k * 64];
            xr2[k] = p2[k * 64]; xr3[k] = p3[k * 64];
        }
    }

    float a0 = 0.f, a1 = 0.f, a2 = 0.f, a3 = 0.f;
    const float* wdp = Wd + (size_t)(g * 256) * BN + lane;
#pragma unroll
    for (int k = 0; k < 4; ++k) {
#pragma unroll 8
        for (int l = 0; l < 64; ++l) {
            float wv = wdp[(size_t)(k * 64 + l) * BN];
            a0 = fmaf(__int_as_float(__builtin_amdgcn_readlane(__float_as_int(xr0[k]), l)), wv, a0);
            a1 = fmaf(__int_as_float(__builtin_amdgcn_readlane(__float_as_int(xr1[k]), l)), wv, a1);
            a2 = fmaf(__int_as_float(__builtin_amdgcn_readlane(__float_as_int(xr2[k]), l)), wv, a2);
            a3 = fmaf(__int_as_float(__builtin_amdgcn_readlane(__float_as_int(xr3[k]), l)), wv, a3);
        }
    }
    hp[g][0][lane] = a0; hp[g][1][lane] = a1;
    hp[g][2][lane] = a2; hp[g][3][lane] = a3;
    __syncthreads();

    if (tid < RPB * BN) {
        int r = tid >> 6, jj = tid & 63;
        float v = bd[jj];
#pragma unroll
        for (int gg = 0; gg < 8; ++gg) v += hp[gg][r][jj];
        hs[r][jj] = v > 0.f ? v : 0.f;
    }
    __syncthreads();

    // up-proj: thread owns float4 column `tid` (512 float4 = H)
    const float4* Wu4 = (const float4*)Wu;
    float4 y0 = ((const float4*)bu)[tid];
    float4 y1 = y0, y2 = y0, y3 = y0;
    for (int jj = 0; jj < BN; ++jj) {
        float4 wv = Wu4[(size_t)jj * (H / 4) + tid];
        float h0 = hs[0][jj], h1 = hs[1][jj], h2 = hs[2][jj], h3 = hs[3][jj];
        y0.x = fmaf(h0, wv.x, y0.x); y0.y = fmaf(h0, wv.y, y0.y);
        y0.z = fmaf(h0, wv.z, y0.z); y0.w = fmaf(h0, wv.w, y0.w);
        y1.x = fmaf(h1, wv.x, y1.x); y1.y = fmaf(h1, wv.y, y1.y);
        y1.z = fmaf(h1, wv.z, y1.z); y1.w = fmaf(h1, wv.w, y1.w);
        y2.x = fmaf(h2, wv.x, y2.x); y2.y = fmaf(h2, wv.y, y2.y);
        y2.z = fmaf(h2, wv.z, y2.z); y2.w = fmaf(h2, wv.w, y2.w);
        y3.x = fmaf(h3, wv.x, y3.x); y3.y = fmaf(h3, wv.y, y3.y);
        y3.z = fmaf(h3, wv.z, y3.z); y3.w = fmaf(h3, wv.w, y3.w);
    }

#pragma unroll
    for (int r = 0; r < RPB; ++r) {
        const float4* xr4 = (const float4*)(x + (size_t)rows[r] * H);
        float4*       o4  = (float4*)(out + (size_t)rows[r] * H);
        float4 xa = xr4[tid];
        float4 yv = (r == 0) ? y0 : (r == 1) ? y1 : (r == 2) ? y2 : y3;
        o4[tid] = make_float4(xa.x + yv.x, xa.y + yv.y, xa.z + yv.z, xa.w + yv.w);
    }
}

// ---------------------------------------------------------------------------
extern "C" void kernel_launch(void* const* d_in, const int* in_sizes, int n_in,
                              void* d_out, int out_size, void* d_ws, size_t ws_size,
                              hipStream_t stream) {
    const float* x  = (const float*)d_in[0];
    const float* Wd = (const float*)d_in[1];
    const float* bd = (const float*)d_in[2];
    const float* Wu = (const float*)d_in[3];
    const float* bu = (const float*)d_in[4];
    const float* Wg = (const float*)d_in[5];
    float* out = (float*)d_out;

    const int nrows = in_sizes[0] / H;                 // B*T = 16384
    float* logits  = (float*)d_ws;                     // nrows floats
    int*   idxlist = (int*)((char*)d_ws + (size_t)nrows * sizeof(float)); // BB*KK ints

    copy_logits_kernel<<<CP_BLOCKS, 256, 0, stream>>>(x, Wg, out, logits, nrows);
    topk_idx_kernel<<<BB, 256, 0, stream>>>(logits, idxlist);
    adapter_kernel<<<(BB * KK) / RPB, 512, 0, stream>>>(x, Wd, bd, Wu, bu, idxlist, out);
}